// Round 10
// baseline (280.785 us; speedup 1.0000x reference)
//
#include <hip/hip_runtime.h>
#include <hip/hip_bf16.h>

// Sizes fixed by setup_inputs()
#define N_EL   1024
#define N_UP   512
#define NNUC   256
#define DIM    256
#define EDIM   32

#define GAIN_F      1.7872135f          // 1/std(silu(N(0,1))), analytic
#define INV_SQRT2_F 0.7071067811865476f

// MEASUREMENT ROUND: each kernel body runs N idempotent iterations so its
// aggregate duration clears the 40-us harness fills and appears in rocprof
// top-5. Per-kernel true time = dispatch dur / N. Output is bit-identical
// to R9 (every iteration recomputes and rewrites the same values).
#define PREP_REP 20
#define EDGE_REP 10
#define OUT_REP  20

typedef __attribute__((ext_vector_type(8))) short bf16x8;
typedef __attribute__((ext_vector_type(4))) short bf16x4;
typedef __attribute__((ext_vector_type(4))) float f32x4;

__device__ __forceinline__ short f2bf(float x) {
    union { __hip_bfloat16 h; short s; } u;
    u.h = __float2bfloat16(x);     // compiler pk-fuses pairs (v_cvt_pk_bf16_f32)
    return u.s;
}

// ---------------------------------------------------------------------------
// K0 prep (R9 body x PREP_REP)
// ---------------------------------------------------------------------------
__global__ __launch_bounds__(256) void prep_kernel(
    const float* __restrict__ up, const float* __restrict__ dn,
    const float* __restrict__ wedge,
    const float* __restrict__ w1, const float* __restrict__ w2,
    const float* __restrict__ elec,
    float* __restrict__ tab_up, float* __restrict__ tab_dn,
    short* __restrict__ wedge_arr,
    short* __restrict__ w1f, short* __restrict__ w2f,
    short* __restrict__ elecb)
{
    const int idx = (blockIdx.x << 8) + threadIdx.x;   // 0..65535

    for (int it = 0; it < PREP_REP; ++it) {
        asm volatile("" ::: "memory");   // force loads to re-execute each iter

        { // spin tables -> C-fragment order (f32)
            const int kt = idx >> 12;
            const int dt = (idx >> 8) & 15;
            const int l  = (idx >> 2) & 63;
            const int r  = idx & 3;
            const int row = (kt << 4) + ((l >> 4) << 2) + r;
            const int col = (dt << 4) + (l & 15);
            tab_up[idx] = up[row * DIM + col];
            tab_dn[idx] = dn[row * DIM + col];
        }
        if (idx < 16 * 64 * 8) {                           // W_edge B-frag (8192)
            const int dt2 = idx >> 9;
            const int l2  = (idx >> 3) & 63;
            const int b   = idx & 7;
            const int j   = ((l2 >> 4) << 3) + b;
            const int d   = (dt2 << 4) + (l2 & 15);
            wedge_arr[idx] = f2bf(wedge[j * DIM + d]);
        }
        { // W1/W2 -> B-frag bf16 (65536 each)
            const int b  = idx & 7;
            const int l  = (idx >> 3) & 63;
            const int q  = (idx >> 9) & 7;
            const int nt = idx >> 12;
            const int j  = (q << 5) + ((l >> 4) << 3) + b;
            const int d  = (nt << 4) + (l & 15);
            w1f[idx] = f2bf(w1[j * DIM + d]);
            w2f[idx] = f2bf(w2[j * DIM + d]);
        }
        { // elec -> row-major bf16, 4 elems/thread
            const f32x4 v = *(const f32x4*)(elec + (idx << 2));
            bf16x4 o;
            o[0] = f2bf(v[0]); o[1] = f2bf(v[1]); o[2] = f2bf(v[2]); o[3] = f2bf(v[3]);
            *(bf16x4*)(elecb + (idx << 2)) = o;
        }
    }
}

// ---------------------------------------------------------------------------
// K1 edge (R9 body x EDGE_REP)
// ---------------------------------------------------------------------------
__global__ __launch_bounds__(256) void edge_kernel(
    const float* __restrict__ eemb,
    const float* __restrict__ tab_up, const float* __restrict__ tab_dn,
    const short* __restrict__ wedge_arr,
    const float* __restrict__ s1p,
    float* __restrict__ agg)
{
    __shared__ float part[4][2][256];      // [wave][e][d]  8 KB
    const int tid  = threadIdx.x;
    const int w    = tid >> 6;
    const int lane = tid & 63;
    const int g    = lane >> 4;
    const int c    = lane & 15;
    const int base = blockIdx.x << 1;      // 2 electrons per block
    const float* __restrict__ tab = (base < N_UP) ? tab_up : tab_dn;

    for (int it = 0; it < EDGE_REP; ++it) {
        asm volatile("" ::: "memory");

        bf16x8 a[2][4];
        #pragma unroll
        for (int e = 0; e < 2; ++e) {
            #pragma unroll
            for (int q = 0; q < 4; ++q) {
                const int kt = (w << 2) + q;
                const float* src = eemb +
                    ((size_t)((base + e) * NNUC + (kt << 4) + c) * EDIM + (g << 3));
                f32x4 lo = *(const f32x4*)(src);
                f32x4 hi = *(const f32x4*)(src + 4);
                union { bf16x8 v; short s[8]; } f;
                f.s[0] = f2bf(lo[0]); f.s[1] = f2bf(lo[1]);
                f.s[2] = f2bf(lo[2]); f.s[3] = f2bf(lo[3]);
                f.s[4] = f2bf(hi[0]); f.s[5] = f2bf(hi[1]);
                f.s[6] = f2bf(hi[2]); f.s[7] = f2bf(hi[3]);
                a[e][q] = f.v;
            }
        }

        const int kt0 = (w << 2);
        f32x4 tn[3][4];
        bf16x8 bn[3];
        #pragma unroll
        for (int d = 0; d < 3; ++d) {
            bn[d] = *(const bf16x8*)(wedge_arr + ((d << 6) + lane) * 8);
            #pragma unroll
            for (int q = 0; q < 4; ++q)
                tn[d][q] = *(const f32x4*)(tab + ((((kt0 + q) << 4) + d) * 64 + lane) * 4);
        }

        const f32x4 zero4 = {0.f, 0.f, 0.f, 0.f};

        #pragma unroll
        for (int dt = 0; dt < 16; ++dt) {
            const int slot = dt % 3;           // compile-time after full unroll
            const bf16x8 bcur = bn[slot];
            f32x4 t0 = tn[slot][0], t1 = tn[slot][1],
                  t2 = tn[slot][2], t3 = tn[slot][3];
            if (dt + 3 < 16) {
                bn[slot] = *(const bf16x8*)(wedge_arr + (((dt + 3) << 6) + lane) * 8);
                #pragma unroll
                for (int q = 0; q < 4; ++q)
                    tn[slot][q] = *(const f32x4*)(tab +
                        ((((kt0 + q) << 4) + dt + 3) * 64 + lane) * 4);
            }
            float p[2] = {0.f, 0.f};
            #pragma unroll
            for (int e = 0; e < 2; ++e) {
                f32x4 cc;
                cc = __builtin_amdgcn_mfma_f32_16x16x32_bf16(a[e][0], bcur, zero4, 0, 0, 0);
                p[e] += cc[0] * t0[0] + cc[1] * t0[1] + cc[2] * t0[2] + cc[3] * t0[3];
                cc = __builtin_amdgcn_mfma_f32_16x16x32_bf16(a[e][1], bcur, zero4, 0, 0, 0);
                p[e] += cc[0] * t1[0] + cc[1] * t1[1] + cc[2] * t1[2] + cc[3] * t1[3];
                cc = __builtin_amdgcn_mfma_f32_16x16x32_bf16(a[e][2], bcur, zero4, 0, 0, 0);
                p[e] += cc[0] * t2[0] + cc[1] * t2[1] + cc[2] * t2[2] + cc[3] * t2[3];
                cc = __builtin_amdgcn_mfma_f32_16x16x32_bf16(a[e][3], bcur, zero4, 0, 0, 0);
                p[e] += cc[0] * t3[0] + cc[1] * t3[1] + cc[2] * t3[2] + cc[3] * t3[3];
            }
            #pragma unroll
            for (int e = 0; e < 2; ++e) {
                float v = p[e];
                v += __shfl_xor(v, 16, 64);
                v += __shfl_xor(v, 32, 64);
                if (lane < 16) part[w][e][(dt << 4) + lane] = v;
            }
        }
        __syncthreads();

        const float s1 = *s1p;
        for (int t = tid; t < 2 * 256; t += 256) {
            const int e = t >> 8;
            const int d = t & 255;
            const float s = part[0][e][d] + part[1][e][d] +
                            part[2][e][d] + part[3][e][d];
            agg[(size_t)(base + e) * DIM + d] = s * s1;
        }
        __syncthreads();   // part[] reused next iteration
    }
}

// ---------------------------------------------------------------------------
// K2 out (R9 body x OUT_REP)
// ---------------------------------------------------------------------------
__global__ __launch_bounds__(512) void out_kernel(
    const short* __restrict__ elecb,
    const short* __restrict__ w1f, const short* __restrict__ w2f,
    const float* __restrict__ elec, const float* __restrict__ agg,
    const float* __restrict__ norm,
    const float* __restrict__ b1, const float* __restrict__ b2,
    const float* __restrict__ s2p,
    float* __restrict__ outp)
{
    __shared__ short h_s[16][264];      // +8 pad -> 2-way banks (free)

    const int tid  = threadIdx.x;
    const int w    = tid >> 6;          // 0..7
    const int lane = tid & 63;
    const int g    = lane >> 4;
    const int c    = lane & 15;
    const int mt   = blockIdx.x >> 2;   // row-tile 0..63
    const int qd   = blockIdx.x & 3;    // quadrant 0..3
    const int mb   = mt << 4;           // 16 rows per row-tile

    for (int it = 0; it < OUT_REP; ++it) {
        asm volatile("" ::: "memory");

        const short* abase = elecb + ((mb + c) << 8) + (g << 3);
        bf16x8 a[8];
        #pragma unroll
        for (int q = 0; q < 8; ++q) a[q] = *(const bf16x8*)(abase + (q << 5));

        const float s2 = *s2p;

        // ---------------- gemm1 (all 16 col-tiles) ----------------
        #pragma unroll
        for (int t = 0; t < 2; ++t) {
            const int ct = (w << 1) + t;
            const short* bb = w1f + (ct << 12) + (lane << 3);
            bf16x8 b[8];
            #pragma unroll
            for (int q = 0; q < 8; ++q) b[q] = *(const bf16x8*)(bb + (q << 9));
            f32x4 acc = {0.f, 0.f, 0.f, 0.f};
            #pragma unroll
            for (int q = 0; q < 8; ++q)
                acc = __builtin_amdgcn_mfma_f32_16x16x32_bf16(a[q], b[q], acc, 0, 0, 0);

            const int n  = (ct << 4) + c;
            const float bv = b1[n];
            #pragma unroll
            for (int r = 0; r < 4; ++r) {
                const int mr = (g << 2) + r;            // 0..15 (C-frag row)
                const int m  = mb + mr;
                const float y = (acc[r] + bv + agg[(m << 8) + n] * norm[m]) * s2;
                const float sig = 1.f / (1.f + __expf(-y));
                h_s[mr][n] = f2bf(GAIN_F * y * sig);
            }
        }
        __syncthreads();

        // ---------------- gemm2 (this block's quadrant; waves 0..3) -------
        if (w < 4) {
            bf16x8 a2[8];                               // row = c, k = q*32+g*8+b
            #pragma unroll
            for (int q = 0; q < 8; ++q)
                a2[q] = *(const bf16x8*)(&h_s[c][(q << 5) + (g << 3)]);

            const int ct = (qd << 2) + w;               // col-tile 0..15, unique
            const short* bb = w2f + (ct << 12) + (lane << 3);
            bf16x8 b[8];
            #pragma unroll
            for (int q = 0; q < 8; ++q) b[q] = *(const bf16x8*)(bb + (q << 9));
            f32x4 acc = {0.f, 0.f, 0.f, 0.f};
            #pragma unroll
            for (int q = 0; q < 8; ++q)
                acc = __builtin_amdgcn_mfma_f32_16x16x32_bf16(a2[q], b[q], acc, 0, 0, 0);

            const int n  = (ct << 4) + c;
            const float bv = b2[n];
            #pragma unroll
            for (int r = 0; r < 4; ++r) {
                const int m = mb + (g << 2) + r;
                const float z = acc[r] + bv;
                const float sig = 1.f / (1.f + __expf(-z));
                const float o = GAIN_F * z * sig;
                outp[(m << 8) + n] = (elec[(m << 8) + n] + o) * INV_SQRT2_F;
            }
        }
        __syncthreads();   // h_s rewritten next iteration
    }
}

// ---------------------------------------------------------------------------
extern "C" void kernel_launch(void* const* d_in, const int* in_sizes, int n_in,
                              void* d_out, int out_size, void* d_ws, size_t ws_size,
                              hipStream_t stream)
{
    const float* elec  = (const float*)d_in[0];
    const float* up    = (const float*)d_in[1];
    const float* dn    = (const float*)d_in[2];
    const float* eemb  = (const float*)d_in[3];
    // d_in[4] = contr: init-time only, unused at runtime
    const float* norm  = (const float*)d_in[5];
    const float* W1    = (const float*)d_in[6];
    const float* b1    = (const float*)d_in[7];
    const float* Wedge = (const float*)d_in[8];
    const float* W2    = (const float*)d_in[9];
    const float* b2    = (const float*)d_in[10];
    const float* s1    = (const float*)d_in[11];
    const float* s2    = (const float*)d_in[12];

    // ws layout: tab_up 65536 f32 | tab_dn 65536 f32 | shorts:
    //   wedge_arr 8192 | w1f 65536 | w2f 65536 | elecb 262144 | agg (f32) 262144
    float* ws     = (float*)d_ws;
    float* tab_up = ws;
    float* tab_dn = ws + 65536;
    short* sbase  = (short*)(ws + 131072);
    short* warr   = sbase;
    short* w1f    = sbase + 8192;
    short* w2f    = sbase + 8192 + 65536;
    short* elecb  = sbase + 8192 + 131072;
    float* agg    = (float*)(sbase + 8192 + 131072 + 262144);

    prep_kernel<<<256, 256, 0, stream>>>(up, dn, Wedge, W1, W2, elec,
                                         tab_up, tab_dn, warr, w1f, w2f, elecb);
    edge_kernel<<<512, 256, 0, stream>>>(eemb, tab_up, tab_dn, warr, s1, agg);
    out_kernel <<<256, 512, 0, stream>>>(elecb, w1f, w2f, elec, agg, norm,
                                         b1, b2, s2, (float*)d_out);
}

// Round 11
// 81.228 us; speedup vs baseline: 3.4567x; 3.4567x over previous
//
#include <hip/hip_runtime.h>
#include <hip/hip_bf16.h>

// Sizes fixed by setup_inputs()
#define N_EL   1024
#define N_UP   512
#define NNUC   256
#define DIM    256
#define EDIM   32
#define KTOT   8192              // NNUC * EDIM, GEMM K dimension

#define GAIN_F      1.7872135f          // 1/std(silu(N(0,1))), analytic
#define INV_SQRT2_F 0.7071067811865476f

typedef __attribute__((ext_vector_type(8))) short bf16x8;
typedef __attribute__((ext_vector_type(4))) short bf16x4;
typedef __attribute__((ext_vector_type(4))) float f32x4;

__device__ __forceinline__ short f2bf(float x) {
    union { __hip_bfloat16 h; short s; } u;
    u.h = __float2bfloat16(x);     // compiler pk-fuses pairs (v_cvt_pk_bf16_f32)
    return u.s;
}

// ---------------------------------------------------------------------------
// K0 prep: w1f/w2f/elecb (as before, idx<65536) + NEW: T fragment tables.
//   T[s][(kt*16+dt)*64 + l][b] = bf16( inp_s[kt][d] * W_edge[j][d] ),
//     j = 8*(l>>4)+b, d = dt*16 + (l&15)    (B-fragment layout, K-tile = kt)
// One thread writes 8 consecutive elements = one bf16x8 (rem*8 is exactly the
// fragment offset). 2048 blocks x 256 threads.
// ---------------------------------------------------------------------------
__global__ __launch_bounds__(256) void prep_kernel(
    const float* __restrict__ up, const float* __restrict__ dn,
    const float* __restrict__ wedge,
    const float* __restrict__ w1, const float* __restrict__ w2,
    const float* __restrict__ elec,
    short* __restrict__ w1f, short* __restrict__ w2f,
    short* __restrict__ elecb, short* __restrict__ Tf)
{
    const int idx = (blockIdx.x << 8) + threadIdx.x;   // 0..524287

    if (idx < 65536) {
        { // W1/W2 -> B-frag bf16 (65536 each)
            const int b  = idx & 7;
            const int l  = (idx >> 3) & 63;
            const int q  = (idx >> 9) & 7;
            const int nt = idx >> 12;
            const int j  = (q << 5) + ((l >> 4) << 3) + b;
            const int d  = (nt << 4) + (l & 15);
            w1f[idx] = f2bf(w1[j * DIM + d]);
            w2f[idx] = f2bf(w2[j * DIM + d]);
        }
        { // elec -> row-major bf16, 4 elems/thread
            const f32x4 v = *(const f32x4*)(elec + (idx << 2));
            bf16x4 o;
            o[0] = f2bf(v[0]); o[1] = f2bf(v[1]); o[2] = f2bf(v[2]); o[3] = f2bf(v[3]);
            *(bf16x4*)(elecb + (idx << 2)) = o;
        }
    }

    { // T fragments: 2 spins x 262144 threads x 8 elements
        const int s   = idx >> 18;             // 0 = up, 1 = down
        const int rem = idx & 262143;
        const int kt  = rem >> 10;             // nucleus 0..255
        const int dt  = (rem >> 6) & 15;
        const int l   = rem & 63;
        const int d   = (dt << 4) + (l & 15);
        const int jb  = (l >> 4) << 3;         // j base
        const float* __restrict__ inp = s ? dn : up;
        const float iv = inp[kt * DIM + d];
        const float* __restrict__ wcol = wedge + d;
        bf16x8 o;
        #pragma unroll
        for (int b = 0; b < 8; ++b)
            o[b] = f2bf(iv * wcol[(jb + b) * DIM]);
        *(bf16x8*)(Tf + ((size_t)s << 21) + ((size_t)rem << 3)) = o;
    }
}

// ---------------------------------------------------------------------------
// K1 edge_gemm: agg = s1 * (E[1024 x 8192] @ T[spin][8192 x 256]).
// 256 blocks x 512 threads (8 waves). Block = 16 rows x 64 cols.
// Wave w: col-tile ct = (cg*4 + w&3), K-half kh = w>>2 -> 128 acc-chained
// MFMAs streaming A (f32->bf16 inline) and B (pre-fragmented T) linearly.
// Wave pairs (w, w+4) LDS-reduce their K-halves; waves 0..3 write agg.
// ---------------------------------------------------------------------------
__global__ __launch_bounds__(512) void edge_gemm(
    const float* __restrict__ eemb,
    const short* __restrict__ Tf,
    const float* __restrict__ s1p,
    float* __restrict__ agg)
{
    __shared__ float red[4][64][4];        // 4 KB

    const int tid  = threadIdx.x;
    const int w    = tid >> 6;             // 0..7
    const int lane = tid & 63;
    const int g    = lane >> 4;
    const int c    = lane & 15;
    const int rb   = blockIdx.x >> 2;      // row-block 0..63
    const int cg   = blockIdx.x & 3;       // col-group 0..3
    const int mb   = rb << 4;
    const int ct   = (cg << 2) + (w & 3);  // col-tile 0..15
    const int kh   = w >> 2;               // K-half

    const short* __restrict__ Tb =
        Tf + ((mb < N_UP) ? 0 : (size_t)1 << 21);
    const float* __restrict__ Arow =
        eemb + (size_t)(mb + c) * KTOT + (kh << 12) + (g << 3);
    const short* __restrict__ Bp =
        Tb + ((size_t)(kh << 7) << 13) + (((ct << 6) + lane) << 3);

    f32x4 acc = {0.f, 0.f, 0.f, 0.f};

    #pragma unroll 8
    for (int k2 = 0; k2 < 128; ++k2) {
        const f32x4 lo = *(const f32x4*)(Arow + (k2 << 5));
        const f32x4 hi = *(const f32x4*)(Arow + (k2 << 5) + 4);
        union { bf16x8 v; short s[8]; } af;
        af.s[0] = f2bf(lo[0]); af.s[1] = f2bf(lo[1]);
        af.s[2] = f2bf(lo[2]); af.s[3] = f2bf(lo[3]);
        af.s[4] = f2bf(hi[0]); af.s[5] = f2bf(hi[1]);
        af.s[6] = f2bf(hi[2]); af.s[7] = f2bf(hi[3]);
        const bf16x8 bf = *(const bf16x8*)(Bp + ((size_t)k2 << 13));
        acc = __builtin_amdgcn_mfma_f32_16x16x32_bf16(af.v, bf, acc, 0, 0, 0);
    }

    if (w >= 4) {
        #pragma unroll
        for (int r = 0; r < 4; ++r) red[w - 4][lane][r] = acc[r];
    }
    __syncthreads();
    if (w < 4) {
        const float s1 = *s1p;
        #pragma unroll
        for (int r = 0; r < 4; ++r) {
            const float v = (acc[r] + red[w][lane][r]) * s1;
            agg[((mb + (g << 2) + r) << 8) + (ct << 4) + c] = v;
        }
    }
}

// ---------------------------------------------------------------------------
// K2 out: gemm1+gemm2 (identical to R9: 256 blocks x 512, redundant gemm1,
// quadrant gemm2).
// ---------------------------------------------------------------------------
__global__ __launch_bounds__(512) void out_kernel(
    const short* __restrict__ elecb,
    const short* __restrict__ w1f, const short* __restrict__ w2f,
    const float* __restrict__ elec, const float* __restrict__ agg,
    const float* __restrict__ norm,
    const float* __restrict__ b1, const float* __restrict__ b2,
    const float* __restrict__ s2p,
    float* __restrict__ outp)
{
    __shared__ short h_s[16][264];      // +8 pad -> 2-way banks (free)

    const int tid  = threadIdx.x;
    const int w    = tid >> 6;          // 0..7
    const int lane = tid & 63;
    const int g    = lane >> 4;
    const int c    = lane & 15;
    const int mt   = blockIdx.x >> 2;   // row-tile 0..63
    const int qd   = blockIdx.x & 3;    // quadrant 0..3
    const int mb   = mt << 4;           // 16 rows per row-tile

    const short* abase = elecb + ((mb + c) << 8) + (g << 3);
    bf16x8 a[8];
    #pragma unroll
    for (int q = 0; q < 8; ++q) a[q] = *(const bf16x8*)(abase + (q << 5));

    const float s2 = *s2p;

    // ---------------- gemm1 (all 16 col-tiles) ----------------
    #pragma unroll
    for (int t = 0; t < 2; ++t) {
        const int ct = (w << 1) + t;
        const short* bb = w1f + (ct << 12) + (lane << 3);
        bf16x8 b[8];
        #pragma unroll
        for (int q = 0; q < 8; ++q) b[q] = *(const bf16x8*)(bb + (q << 9));
        f32x4 acc = {0.f, 0.f, 0.f, 0.f};
        #pragma unroll
        for (int q = 0; q < 8; ++q)
            acc = __builtin_amdgcn_mfma_f32_16x16x32_bf16(a[q], b[q], acc, 0, 0, 0);

        const int n  = (ct << 4) + c;
        const float bv = b1[n];
        #pragma unroll
        for (int r = 0; r < 4; ++r) {
            const int mr = (g << 2) + r;            // 0..15 (C-frag row)
            const int m  = mb + mr;
            const float y = (acc[r] + bv + agg[(m << 8) + n] * norm[m]) * s2;
            const float sig = 1.f / (1.f + __expf(-y));
            h_s[mr][n] = f2bf(GAIN_F * y * sig);
        }
    }
    __syncthreads();

    // ---------------- gemm2 (this block's quadrant; waves 0..3) -------
    if (w < 4) {
        bf16x8 a2[8];                               // row = c, k = q*32+g*8+b
        #pragma unroll
        for (int q = 0; q < 8; ++q)
            a2[q] = *(const bf16x8*)(&h_s[c][(q << 5) + (g << 3)]);

        const int ct = (qd << 2) + w;               // col-tile 0..15, unique
        const short* bb = w2f + (ct << 12) + (lane << 3);
        bf16x8 b[8];
        #pragma unroll
        for (int q = 0; q < 8; ++q) b[q] = *(const bf16x8*)(bb + (q << 9));
        f32x4 acc = {0.f, 0.f, 0.f, 0.f};
        #pragma unroll
        for (int q = 0; q < 8; ++q)
            acc = __builtin_amdgcn_mfma_f32_16x16x32_bf16(a2[q], b[q], acc, 0, 0, 0);

        const int n  = (ct << 4) + c;
        const float bv = b2[n];
        #pragma unroll
        for (int r = 0; r < 4; ++r) {
            const int m = mb + (g << 2) + r;
            const float z = acc[r] + bv;
            const float sig = 1.f / (1.f + __expf(-z));
            const float o = GAIN_F * z * sig;
            outp[(m << 8) + n] = (elec[(m << 8) + n] + o) * INV_SQRT2_F;
        }
    }
}

// ---------------------------------------------------------------------------
extern "C" void kernel_launch(void* const* d_in, const int* in_sizes, int n_in,
                              void* d_out, int out_size, void* d_ws, size_t ws_size,
                              hipStream_t stream)
{
    const float* elec  = (const float*)d_in[0];
    const float* up    = (const float*)d_in[1];
    const float* dn    = (const float*)d_in[2];
    const float* eemb  = (const float*)d_in[3];
    // d_in[4] = contr: init-time only, unused at runtime
    const float* norm  = (const float*)d_in[5];
    const float* W1    = (const float*)d_in[6];
    const float* b1    = (const float*)d_in[7];
    const float* Wedge = (const float*)d_in[8];
    const float* W2    = (const float*)d_in[9];
    const float* b2    = (const float*)d_in[10];
    const float* s1    = (const float*)d_in[11];
    const float* s2    = (const float*)d_in[12];

    // ws layout (shorts): w1f 65536 | w2f 65536 | elecb 262144 |
    //   Tf 4194304 (2 spins x 2M) | then agg f32 262144   (~10.2 MB total)
    short* sbase = (short*)d_ws;
    short* w1f   = sbase;
    short* w2f   = sbase + 65536;
    short* elecb = sbase + 131072;
    short* Tf    = sbase + 393216;
    float* agg   = (float*)(sbase + 393216 + 4194304);

    prep_kernel<<<2048, 256, 0, stream>>>(up, dn, Wedge, W1, W2, elec,
                                          w1f, w2f, elecb, Tf);
    edge_gemm  <<<256, 512, 0, stream>>>(eemb, Tf, s1, agg);
    out_kernel <<<256, 512, 0, stream>>>(elecb, w1f, w2f, elec, agg, norm,
                                         b1, b2, s2, (float*)d_out);
}

// Round 12
// 32.880 us; speedup vs baseline: 8.5397x; 2.4704x over previous
//
#include <hip/hip_runtime.h>
#include <hip/hip_bf16.h>

// Sizes fixed by setup_inputs()
#define N_EL   1024
#define N_UP   512
#define NNUC   256
#define DIM    256
#define EDIM   32
#define KTOT   8192              // NNUC * EDIM, GEMM K dimension

#define GAIN_F      1.7872135f          // 1/std(silu(N(0,1))), analytic
#define INV_SQRT2_F 0.7071067811865476f

typedef __attribute__((ext_vector_type(8))) short bf16x8;
typedef __attribute__((ext_vector_type(4))) short bf16x4;
typedef __attribute__((ext_vector_type(4))) float f32x4;

__device__ __forceinline__ short f2bf(float x) {
    union { __hip_bfloat16 h; short s; } u;
    u.h = __float2bfloat16(x);     // compiler pk-fuses pairs (v_cvt_pk_bf16_f32)
    return u.s;
}

// ---------------------------------------------------------------------------
// K0 prep (identical to R11): w1f/w2f/elecb + T fragment tables.
//   Tf[s][(kt*16+dt)*64 + l][b] = bf16( inp_s[kt][d] * W_edge[j][d] ),
//     j = 8*(l>>4)+b, d = dt*16 + (l&15)
// ---------------------------------------------------------------------------
__global__ __launch_bounds__(256) void prep_kernel(
    const float* __restrict__ up, const float* __restrict__ dn,
    const float* __restrict__ wedge,
    const float* __restrict__ w1, const float* __restrict__ w2,
    const float* __restrict__ elec,
    short* __restrict__ w1f, short* __restrict__ w2f,
    short* __restrict__ elecb, short* __restrict__ Tf)
{
    const int idx = (blockIdx.x << 8) + threadIdx.x;   // 0..524287

    if (idx < 65536) {
        { // W1/W2 -> B-frag bf16 (65536 each)
            const int b  = idx & 7;
            const int l  = (idx >> 3) & 63;
            const int q  = (idx >> 9) & 7;
            const int nt = idx >> 12;
            const int j  = (q << 5) + ((l >> 4) << 3) + b;
            const int d  = (nt << 4) + (l & 15);
            w1f[idx] = f2bf(w1[j * DIM + d]);
            w2f[idx] = f2bf(w2[j * DIM + d]);
        }
        { // elec -> row-major bf16, 4 elems/thread
            const f32x4 v = *(const f32x4*)(elec + (idx << 2));
            bf16x4 o;
            o[0] = f2bf(v[0]); o[1] = f2bf(v[1]); o[2] = f2bf(v[2]); o[3] = f2bf(v[3]);
            *(bf16x4*)(elecb + (idx << 2)) = o;
        }
    }

    { // T fragments: 2 spins x 262144 threads x 8 elements
        const int s   = idx >> 18;             // 0 = up, 1 = down
        const int rem = idx & 262143;
        const int kt  = rem >> 10;             // nucleus 0..255
        const int dt  = (rem >> 6) & 15;
        const int l   = rem & 63;
        const int d   = (dt << 4) + (l & 15);
        const int jb  = (l >> 4) << 3;         // j base
        const float* __restrict__ inp = s ? dn : up;
        const float iv = inp[kt * DIM + d];
        const float* __restrict__ wcol = wedge + d;
        bf16x8 o;
        #pragma unroll
        for (int b = 0; b < 8; ++b)
            o[b] = f2bf(iv * wcol[(jb + b) * DIM]);
        *(bf16x8*)(Tf + ((size_t)s << 21) + ((size_t)rem << 3)) = o;
    }
}

// ---------------------------------------------------------------------------
// K1 edge_gemm v2: P[kp] = E[rows, K-chunk] @ T[spin][K-chunk, 256].
// 256 blocks x 512 threads. block = (kp = bid&7 -> XCD-affine K-part,
// rt = bid>>3 -> M=32 rows). 8 sub-chunks of K=128, software-pipelined:
//   issue A loads (HBM->regs) / B loads (L2->regs) for sub+1,
//   ds_read A-frags[cur] -> 16 MFMAs (4 indep chains),
//   cvt+ds_write A[sub+1] (T14 write-late), barrier.
// A-frags shared by all waves via 16 KB dbuf LDS; B per-wave in regs.
// ---------------------------------------------------------------------------
__global__ __launch_bounds__(512) void edge_gemm(
    const float* __restrict__ eemb,
    const short* __restrict__ Tf,
    float* __restrict__ P)             // [8][1024][256] f32 partials
{
    __shared__ short A_lds[2][4096];   // [buf][frag(8) * lane(64) * 8] = 8 KB/buf

    const int tid  = threadIdx.x;
    const int w    = tid >> 6;          // 0..7
    const int lane = tid & 63;
    const int g    = lane >> 4;
    const int c    = lane & 15;
    const int kp   = blockIdx.x & 7;    // K-part (XCD round-robin)
    const int rt   = blockIdx.x >> 3;   // row-tile 0..31
    const int rb   = rt << 5;           // 32 rows
    const int kb   = kp << 10;          // K-chunk base

    const short* __restrict__ Tb = Tf + ((rb < N_UP) ? 0 : (1 << 21));

    // staging role: thread handles frag f = (r<<2)+q, element lane
    const int f  = w;                   // 8 frags, one per wave-id group
    const int r_ = f >> 2;
    const int q_ = f & 3;
    const float* __restrict__ Asrc = eemb
        + (size_t)(rb + (r_ << 4) + c) * KTOT
        + kb + (q_ << 5) + (g << 3);

    f32x4 s_lo, s_hi;                   // in-flight A stage regs
    bf16x8 bA[8], bB[8];                // B double-buffer (compile-time indexed)

    auto STAGE_LOAD = [&](int sub) {
        const float* p = Asrc + (sub << 7);        // sub*128 in k
        s_lo = *(const f32x4*)p;
        s_hi = *(const f32x4*)(p + 4);
    };
    auto STAGE_WRITE = [&](int buf) {
        union { bf16x8 v; short s[8]; } o;
        o.s[0] = f2bf(s_lo[0]); o.s[1] = f2bf(s_lo[1]);
        o.s[2] = f2bf(s_lo[2]); o.s[3] = f2bf(s_lo[3]);
        o.s[4] = f2bf(s_hi[0]); o.s[5] = f2bf(s_hi[1]);
        o.s[6] = f2bf(s_hi[2]); o.s[7] = f2bf(s_hi[3]);
        *(bf16x8*)(&A_lds[buf][(f << 9) + (lane << 3)]) = o.v;
    };
    auto LOADB = [&](int sub, bf16x8 (&bd)[8]) {
        #pragma unroll
        for (int t = 0; t < 2; ++t) {
            const int ct = (w << 1) + t;
            #pragma unroll
            for (int q = 0; q < 4; ++q) {
                const int ktg = (kp << 5) + (sub << 2) + q;
                bd[(t << 2) + q] = *(const bf16x8*)(
                    Tb + (((((ktg << 4) + ct) << 6) + lane) << 3));
            }
        }
    };

    f32x4 acc[2][2] = {{{0.f,0.f,0.f,0.f},{0.f,0.f,0.f,0.f}},
                       {{0.f,0.f,0.f,0.f},{0.f,0.f,0.f,0.f}}};

    auto COMPUTE = [&](int buf, bf16x8 (&bc)[8]) {
        bf16x8 a[2][4];
        #pragma unroll
        for (int rr = 0; rr < 2; ++rr)
            #pragma unroll
            for (int q = 0; q < 4; ++q)
                a[rr][q] = *(const bf16x8*)(
                    &A_lds[buf][((((rr << 2) + q)) << 9) + (lane << 3)]);
        #pragma unroll
        for (int q = 0; q < 4; ++q) {
            acc[0][0] = __builtin_amdgcn_mfma_f32_16x16x32_bf16(a[0][q], bc[q],     acc[0][0], 0, 0, 0);
            acc[0][1] = __builtin_amdgcn_mfma_f32_16x16x32_bf16(a[0][q], bc[4 + q], acc[0][1], 0, 0, 0);
            acc[1][0] = __builtin_amdgcn_mfma_f32_16x16x32_bf16(a[1][q], bc[q],     acc[1][0], 0, 0, 0);
            acc[1][1] = __builtin_amdgcn_mfma_f32_16x16x32_bf16(a[1][q], bc[4 + q], acc[1][1], 0, 0, 0);
        }
    };

    // prologue: stage A(0), load B(0)
    STAGE_LOAD(0);
    LOADB(0, bA);
    STAGE_WRITE(0);
    __syncthreads();

    #pragma unroll
    for (int sub = 0; sub < 8; ++sub) {
        if ((sub & 1) == 0) {
            if (sub < 7) { STAGE_LOAD(sub + 1); LOADB(sub + 1, bB); }
            COMPUTE(0, bA);
        } else {
            if (sub < 7) { STAGE_LOAD(sub + 1); LOADB(sub + 1, bA); }
            COMPUTE(1, bB);
        }
        if (sub < 7) STAGE_WRITE((sub & 1) ^ 1);   // write-late (T14)
        __syncthreads();
    }

    // epilogue: write kp-partial (C-frag: row = 4g+j, col = c)
    float* __restrict__ Pp = P + ((size_t)kp << 18);
    #pragma unroll
    for (int rr = 0; rr < 2; ++rr)
        #pragma unroll
        for (int t = 0; t < 2; ++t) {
            const int ct = (w << 1) + t;
            #pragma unroll
            for (int j = 0; j < 4; ++j) {
                const int row = rb + (rr << 4) + (g << 2) + j;
                Pp[(row << 8) + (ct << 4) + c] = acc[rr][t][j];
            }
        }
}

// ---------------------------------------------------------------------------
// K2 out: gemm1+gemm2 (R9 structure); gemm1 epilogue now sums the 8
// K-partials and applies s1.
// ---------------------------------------------------------------------------
__global__ __launch_bounds__(512) void out_kernel(
    const short* __restrict__ elecb,
    const short* __restrict__ w1f, const short* __restrict__ w2f,
    const float* __restrict__ elec, const float* __restrict__ P,
    const float* __restrict__ norm,
    const float* __restrict__ b1, const float* __restrict__ b2,
    const float* __restrict__ s1p, const float* __restrict__ s2p,
    float* __restrict__ outp)
{
    __shared__ short h_s[16][264];      // +8 pad -> 2-way banks (free)

    const int tid  = threadIdx.x;
    const int w    = tid >> 6;          // 0..7
    const int lane = tid & 63;
    const int g    = lane >> 4;
    const int c    = lane & 15;
    const int mt   = blockIdx.x >> 2;   // row-tile 0..63
    const int qd   = blockIdx.x & 3;    // quadrant 0..3
    const int mb   = mt << 4;           // 16 rows per row-tile

    const short* abase = elecb + ((mb + c) << 8) + (g << 3);
    bf16x8 a[8];
    #pragma unroll
    for (int q = 0; q < 8; ++q) a[q] = *(const bf16x8*)(abase + (q << 5));

    const float s1 = *s1p;
    const float s2 = *s2p;

    // ---------------- gemm1 (all 16 col-tiles) ----------------
    #pragma unroll
    for (int t = 0; t < 2; ++t) {
        const int ct = (w << 1) + t;
        const short* bb = w1f + (ct << 12) + (lane << 3);
        bf16x8 b[8];
        #pragma unroll
        for (int q = 0; q < 8; ++q) b[q] = *(const bf16x8*)(bb + (q << 9));
        f32x4 acc = {0.f, 0.f, 0.f, 0.f};
        #pragma unroll
        for (int q = 0; q < 8; ++q)
            acc = __builtin_amdgcn_mfma_f32_16x16x32_bf16(a[q], b[q], acc, 0, 0, 0);

        const int n  = (ct << 4) + c;
        const float bv = b1[n];
        #pragma unroll
        for (int r = 0; r < 4; ++r) {
            const int mr = (g << 2) + r;            // 0..15 (C-frag row)
            const int m  = mb + mr;
            float aggv = 0.f;
            #pragma unroll
            for (int kp = 0; kp < 8; ++kp)
                aggv += P[((size_t)kp << 18) + (m << 8) + n];
            const float y = (acc[r] + bv + aggv * s1 * norm[m]) * s2;
            const float sig = 1.f / (1.f + __expf(-y));
            h_s[mr][n] = f2bf(GAIN_F * y * sig);
        }
    }
    __syncthreads();

    // ---------------- gemm2 (this block's quadrant; waves 0..3) -------
    if (w < 4) {
        bf16x8 a2[8];                               // row = c, k = q*32+g*8+b
        #pragma unroll
        for (int q = 0; q < 8; ++q)
            a2[q] = *(const bf16x8*)(&h_s[c][(q << 5) + (g << 3)]);

        const int ct = (qd << 2) + w;               // col-tile 0..15, unique
        const short* bb = w2f + (ct << 12) + (lane << 3);
        bf16x8 b[8];
        #pragma unroll
        for (int q = 0; q < 8; ++q) b[q] = *(const bf16x8*)(bb + (q << 9));
        f32x4 acc = {0.f, 0.f, 0.f, 0.f};
        #pragma unroll
        for (int q = 0; q < 8; ++q)
            acc = __builtin_amdgcn_mfma_f32_16x16x32_bf16(a2[q], b[q], acc, 0, 0, 0);

        const int n  = (ct << 4) + c;
        const float bv = b2[n];
        #pragma unroll
        for (int r = 0; r < 4; ++r) {
            const int m = mb + (g << 2) + r;
            const float z = acc[r] + bv;
            const float sig = 1.f / (1.f + __expf(-z));
            const float o = GAIN_F * z * sig;
            outp[(m << 8) + n] = (elec[(m << 8) + n] + o) * INV_SQRT2_F;
        }
    }
}

// ---------------------------------------------------------------------------
extern "C" void kernel_launch(void* const* d_in, const int* in_sizes, int n_in,
                              void* d_out, int out_size, void* d_ws, size_t ws_size,
                              hipStream_t stream)
{
    const float* elec  = (const float*)d_in[0];
    const float* up    = (const float*)d_in[1];
    const float* dn    = (const float*)d_in[2];
    const float* eemb  = (const float*)d_in[3];
    // d_in[4] = contr: init-time only, unused at runtime
    const float* norm  = (const float*)d_in[5];
    const float* W1    = (const float*)d_in[6];
    const float* b1    = (const float*)d_in[7];
    const float* Wedge = (const float*)d_in[8];
    const float* W2    = (const float*)d_in[9];
    const float* b2    = (const float*)d_in[10];
    const float* s1    = (const float*)d_in[11];
    const float* s2    = (const float*)d_in[12];

    // ws layout (shorts): w1f 65536 | w2f 65536 | elecb 262144 |
    //   Tf 4194304 | then P f32 8*262144 (8 MB)   (~17.2 MB total, ws = 256 MB)
    short* sbase = (short*)d_ws;
    short* w1f   = sbase;
    short* w2f   = sbase + 65536;
    short* elecb = sbase + 131072;
    short* Tf    = sbase + 393216;
    float* P     = (float*)(sbase + 393216 + 4194304);

    prep_kernel<<<2048, 256, 0, stream>>>(up, dn, Wedge, W1, W2, elec,
                                          w1f, w2f, elecb, Tf);
    edge_gemm  <<<256, 512, 0, stream>>>(eemb, Tf, P);
    out_kernel <<<256, 512, 0, stream>>>(elecb, w1f, w2f, elec, P, norm,
                                         b1, b2, s1, s2, (float*)d_out);
}